// Round 1
// baseline (2446.635 us; speedup 1.0000x reference)
//
#include <hip/hip_runtime.h>
#include <cstdint>
#include <cstddef>

#define NPIX 9216          // 96*96
#define NB 2
#define NC 256
#define RC 64
#define TK 16
#define NROWS (NB * NPIX)  // 18432
#define SLICES 4
#define SLICE_COLS (NPIX / SLICES)  // 2304
#define TCOLS 128

// ---------------- K1: 1x1 conv reduce + L2 normalize -> nf[NROWS][RC] ----------------
__global__ __launch_bounds__(256) void k_reduce_norm(
    const float* __restrict__ x, const float* __restrict__ wr,
    float* __restrict__ nf) {
  // stage w_reduce transposed: wl[c][r], stride 68 floats (16B-aligned, breaks bank stride)
  __shared__ float wl[NC * 68];
  const int tid = threadIdx.x;
#pragma unroll
  for (int i = 0; i < 64; ++i) wl[tid * 68 + i] = wr[i * NC + tid];
  __syncthreads();

  const int p = blockIdx.x * 256 + tid;     // flat row = b*NPIX + n
  const int b = p >= NPIX;
  const int n = p - b * NPIX;
  const float* xp = x + (size_t)b * NC * NPIX + n;

  float4 acc[16];
#pragma unroll
  for (int i = 0; i < 16; ++i) acc[i] = make_float4(0.f, 0.f, 0.f, 0.f);

  for (int c = 0; c < NC; ++c) {
    const float xv = xp[(size_t)c * NPIX];          // coalesced across lanes
    const float4* w4 = (const float4*)(wl + c * 68);  // broadcast reads
#pragma unroll
    for (int i = 0; i < 16; ++i) {
      float4 w = w4[i];
      acc[i].x += w.x * xv; acc[i].y += w.y * xv;
      acc[i].z += w.z * xv; acc[i].w += w.w * xv;
    }
  }

  float ssq = 0.f;
#pragma unroll
  for (int i = 0; i < 16; ++i)
    ssq += acc[i].x * acc[i].x + acc[i].y * acc[i].y +
           acc[i].z * acc[i].z + acc[i].w * acc[i].w;
  const float inv = 1.f / fmaxf(sqrtf(ssq), 1e-12f);

  float4* o = (float4*)(nf + (size_t)p * RC);
#pragma unroll
  for (int i = 0; i < 16; ++i) {
    float4 v = acc[i];
    o[i] = make_float4(v.x * inv, v.y * inv, v.z * inv, v.w * inv);
  }
}

// ---------------- K2: streaming sim + exact per-slice top-16 ----------------
// grid: 72 rowblocks x 4 col-slices. Thread owns one row; top-16 kept sorted
// ASCENDING in registers (val[0] = current min / gate).
__global__ __launch_bounds__(256) void k_sim_topk(
    const float* __restrict__ nf, float* __restrict__ pval, int* __restrict__ pidx) {
  const int rb = blockIdx.x >> 2;
  const int sl = blockIdx.x & 3;
  const int tid = threadIdx.x;
  const int row = rb * 256 + tid;
  const int b = row >= NPIX;
  const float* nfb = nf + (size_t)b * NPIX * RC;

  float4 rf[16];
  const float4* r4 = (const float4*)(nf + (size_t)row * RC);
#pragma unroll
  for (int i = 0; i < 16; ++i) rf[i] = r4[i];

  float val[TK];
  int idx[TK];
#pragma unroll
  for (int i = 0; i < TK; ++i) { val[i] = -2.f; idx[i] = 0; }  // sims are in [-1,1]

  __shared__ float tile[TCOLS * RC];  // 32 KB
  const int col0 = sl * SLICE_COLS;

  for (int t = 0; t < SLICE_COLS / TCOLS; ++t) {
    const int cb = col0 + t * TCOLS;
    {
      const float4* src = (const float4*)(nfb + (size_t)cb * RC);
      float4* dst = (float4*)tile;
#pragma unroll
      for (int i = 0; i < 8; ++i) dst[i * 256 + tid] = src[i * 256 + tid];
    }
    __syncthreads();

    for (int j = 0; j < TCOLS; ++j) {
      const float4* cv = (const float4*)(tile + j * RC);  // broadcast (same addr all lanes)
      float s = 0.f;
#pragma unroll
      for (int i = 0; i < 16; ++i) {
        float4 c4 = cv[i];
        s += rf[i].x * c4.x + rf[i].y * c4.y + rf[i].z * c4.z + rf[i].w * c4.w;
      }
      if (s > val[0]) {  // gate: beats current 16th-largest
        const int m = cb + j;
        float nv[TK];
        int ni[TK];
#pragma unroll
        for (int i = 0; i < TK - 1; ++i) {
          nv[i] = fminf(fmaxf(s, val[i]), val[i + 1]);
          ni[i] = (s > val[i]) ? ((s > val[i + 1]) ? idx[i + 1] : m) : idx[i];
        }
        nv[TK - 1] = fmaxf(s, val[TK - 1]);
        ni[TK - 1] = (s > val[TK - 1]) ? m : idx[TK - 1];
#pragma unroll
        for (int i = 0; i < TK; ++i) { val[i] = nv[i]; idx[i] = ni[i]; }
      }
    }
    __syncthreads();
  }

  // store DESCENDING (ties within slice: older/lower index first by construction)
  const size_t o = ((size_t)row * SLICES + sl) * TK;
#pragma unroll
  for (int i = 0; i < TK; ++i) {
    pval[o + i] = val[TK - 1 - i];
    pidx[o + i] = idx[TK - 1 - i];
  }
}

// ---------------- K3a: 4-way merge of slice top-16s + gather + mean ----------------
__global__ __launch_bounds__(256) void k_merge_gather(
    const float* __restrict__ nf, const float* __restrict__ pval,
    const int* __restrict__ pidx, float* __restrict__ corr) {
  const int row = blockIdx.x * 256 + threadIdx.x;
  const int b = row >= NPIX;
  const float* nfb = nf + (size_t)b * NPIX * RC;
  const size_t base = (size_t)row * SLICES * TK;

  int p0 = 0, p1 = 0, p2 = 0, p3 = 0;
  float4 acc[16];
#pragma unroll
  for (int i = 0; i < 16; ++i) acc[i] = make_float4(0.f, 0.f, 0.f, 0.f);

  for (int k = 0; k < TK; ++k) {
    float h0 = (p0 < TK) ? pval[base + 0 * TK + p0] : -1e30f;
    float h1 = (p1 < TK) ? pval[base + 1 * TK + p1] : -1e30f;
    float h2 = (p2 < TK) ? pval[base + 2 * TK + p2] : -1e30f;
    float h3 = (p3 < TK) ? pval[base + 3 * TK + p3] : -1e30f;
    // strict > keeps earliest slice (lowest column index) on ties, matching lax.top_k
    float best = h0; int bs = 0;
    if (h1 > best) { best = h1; bs = 1; }
    if (h2 > best) { best = h2; bs = 2; }
    if (h3 > best) { best = h3; bs = 3; }
    const int pb = (bs == 0) ? p0 : (bs == 1) ? p1 : (bs == 2) ? p2 : p3;
    const int m = pidx[base + (size_t)bs * TK + pb];
    p0 += (bs == 0); p1 += (bs == 1); p2 += (bs == 2); p3 += (bs == 3);

    const float4* g = (const float4*)(nfb + (size_t)m * RC);
#pragma unroll
    for (int i = 0; i < 16; ++i) {
      float4 v = g[i];
      acc[i].x += v.x; acc[i].y += v.y; acc[i].z += v.z; acc[i].w += v.w;
    }
  }

  float4* o = (float4*)(corr + (size_t)row * RC);
#pragma unroll
  for (int i = 0; i < 16; ++i)
    o[i] = make_float4(acc[i].x * 0.0625f, acc[i].y * 0.0625f,
                       acc[i].z * 0.0625f, acc[i].w * 0.0625f);
}

// ---------------- K3b: proj back to C channels + residual add ----------------
// grid: 72 pixelgroups x 4 channel-quarters
__global__ __launch_bounds__(256) void k_proj_add(
    const float* __restrict__ x, const float* __restrict__ wp,
    const float* __restrict__ corr, float* __restrict__ out) {
  const int pg = blockIdx.x >> 2;
  const int cq = blockIdx.x & 3;
  const int tid = threadIdx.x;

  __shared__ float wl[64 * RC];  // 16 KB: w_proj rows [cq*64, cq*64+64)
  {
    const float4* src = (const float4*)(wp + (size_t)cq * 64 * RC);
    float4* dst = (float4*)wl;
#pragma unroll
    for (int i = 0; i < 4; ++i) dst[i * 256 + tid] = src[i * 256 + tid];
  }

  const int p = pg * 256 + tid;
  const int b = p >= NPIX;
  const int n = p - b * NPIX;

  float4 cr[16];
  const float4* c4 = (const float4*)(corr + (size_t)p * RC);
#pragma unroll
  for (int i = 0; i < 16; ++i) cr[i] = c4[i];
  __syncthreads();

  const size_t xb = (size_t)b * NC * NPIX + n;
  for (int cl = 0; cl < 64; ++cl) {
    const float4* w4 = (const float4*)(wl + cl * RC);  // broadcast
    float s = 0.f;
#pragma unroll
    for (int i = 0; i < 16; ++i) {
      float4 w = w4[i];
      s += w.x * cr[i].x + w.y * cr[i].y + w.z * cr[i].z + w.w * cr[i].w;
    }
    const int c = cq * 64 + cl;
    const size_t oi = xb + (size_t)c * NPIX;
    out[oi] = x[oi] + s;  // coalesced across lanes
  }
}

extern "C" void kernel_launch(void* const* d_in, const int* in_sizes, int n_in,
                              void* d_out, int out_size, void* d_ws, size_t ws_size,
                              hipStream_t stream) {
  const float* x = (const float*)d_in[0];
  const float* wr = (const float*)d_in[1];
  const float* wp = (const float*)d_in[2];
  float* out = (float*)d_out;

  char* ws = (char*)d_ws;
  const size_t nf_bytes = (size_t)NROWS * RC * 4;            // 4.72 MB
  const size_t pv_bytes = (size_t)NROWS * SLICES * TK * 4;   // 4.72 MB
  float* nf = (float*)ws;
  float* pval = (float*)(ws + nf_bytes);
  int* pidx = (int*)(ws + nf_bytes + pv_bytes);
  float* corr = (float*)(ws + nf_bytes + 2 * pv_bytes);      // total ~18.9 MB

  hipLaunchKernelGGL(k_reduce_norm, dim3(NROWS / 256), dim3(256), 0, stream, x, wr, nf);
  hipLaunchKernelGGL(k_sim_topk, dim3((NROWS / 256) * SLICES), dim3(256), 0, stream,
                     nf, pval, pidx);
  hipLaunchKernelGGL(k_merge_gather, dim3(NROWS / 256), dim3(256), 0, stream,
                     nf, pval, pidx, corr);
  hipLaunchKernelGGL(k_proj_add, dim3((NROWS / 256) * 4), dim3(256), 0, stream,
                     x, wp, corr, out);
}

// Round 2
// 1313.114 us; speedup vs baseline: 1.8632x; 1.8632x over previous
//
#include <hip/hip_runtime.h>
#include <cstdint>
#include <cstddef>

#define NPIX 9216          // 96*96
#define NB 2
#define NC 256
#define RC 64
#define TK 16
#define NROWS (NB * NPIX)  // 18432
#define CT 128             // cols per LDS tile in k_sim
#define HALF_COLS 4608
#define NT (HALF_COLS / CT)  // 36
#define NS 8               // partial lists per row (2 halves x 4 quads)

typedef unsigned short ushort_t;
typedef unsigned int uint_t;
typedef __bf16 bf16x8 __attribute__((ext_vector_type(8)));
typedef float f32x4 __attribute__((ext_vector_type(4)));

// RNE float->bf16 bit pattern
__device__ __forceinline__ uint_t f2bf(float x) {
  uint_t u = __float_as_uint(x);
  return (u + 0x7FFFu + ((u >> 16) & 1u)) >> 16;
}

// ---------------- K1: 1x1 conv reduce + L2 normalize -> nf[NROWS][RC] ----------------
__global__ __launch_bounds__(256) void k_reduce_norm(
    const float* __restrict__ x, const float* __restrict__ wr,
    float* __restrict__ nf) {
  __shared__ float wl[NC * 68];
  const int tid = threadIdx.x;
#pragma unroll
  for (int i = 0; i < 64; ++i) wl[tid * 68 + i] = wr[i * NC + tid];
  __syncthreads();

  const int p = blockIdx.x * 256 + tid;
  const int b = p >= NPIX;
  const int n = p - b * NPIX;
  const float* xp = x + (size_t)b * NC * NPIX + n;

  float4 acc[16];
#pragma unroll
  for (int i = 0; i < 16; ++i) acc[i] = make_float4(0.f, 0.f, 0.f, 0.f);

  for (int c = 0; c < NC; ++c) {
    const float xv = xp[(size_t)c * NPIX];
    const float4* w4 = (const float4*)(wl + c * 68);
#pragma unroll
    for (int i = 0; i < 16; ++i) {
      float4 w = w4[i];
      acc[i].x += w.x * xv; acc[i].y += w.y * xv;
      acc[i].z += w.z * xv; acc[i].w += w.w * xv;
    }
  }

  float ssq = 0.f;
#pragma unroll
  for (int i = 0; i < 16; ++i)
    ssq += acc[i].x * acc[i].x + acc[i].y * acc[i].y +
           acc[i].z * acc[i].z + acc[i].w * acc[i].w;
  const float inv = 1.f / fmaxf(sqrtf(ssq), 1e-12f);

  float4* o = (float4*)(nf + (size_t)p * RC);
#pragma unroll
  for (int i = 0; i < 16; ++i) {
    float4 v = acc[i];
    o[i] = make_float4(v.x * inv, v.y * inv, v.z * inv, v.w * inv);
  }
}

// ---------------- K1b: split nf -> bf16 hi/lo ----------------
__global__ __launch_bounds__(256) void k_split(
    const float* __restrict__ nf, ushort_t* __restrict__ hi, ushort_t* __restrict__ lo) {
  const int t = blockIdx.x * 256 + threadIdx.x;  // 8 floats per thread
  const float4* s = (const float4*)(nf + (size_t)t * 8);
  float4 a = s[0], b = s[1];
  float v[8] = {a.x, a.y, a.z, a.w, b.x, b.y, b.z, b.w};
  uint_t hs[8], ls[8];
#pragma unroll
  for (int i = 0; i < 8; ++i) {
    hs[i] = f2bf(v[i]);
    float hf = __uint_as_float(hs[i] << 16);
    ls[i] = f2bf(v[i] - hf);
  }
  uint4 ho = make_uint4(hs[0] | (hs[1] << 16), hs[2] | (hs[3] << 16),
                        hs[4] | (hs[5] << 16), hs[6] | (hs[7] << 16));
  uint4 lov = make_uint4(ls[0] | (ls[1] << 16), ls[2] | (ls[3] << 16),
                         ls[4] | (ls[5] << 16), ls[6] | (ls[7] << 16));
  ((uint4*)hi)[t] = ho;
  ((uint4*)lo)[t] = lov;
}

// ---------------- K2: MFMA sim + per-lane exact top-16 ----------------
// grid: 288 rowblocks x 2 col-halves. Block = 4 waves, wave w owns rows
// rb*64 + 16w + (lane&15). A-operand = streamed cols, B-operand = fixed rows,
// so D[m=col][n=row]: lane&15 = this lane's ROW (fixed), quad*4+reg = col.
__global__ __launch_bounds__(256) void k_sim_topk(
    const ushort_t* __restrict__ nf_hi, const ushort_t* __restrict__ nf_lo,
    float* __restrict__ pval, int* __restrict__ pidx) {
  __shared__ ushort_t sh[CT * 72];  // cols hi, stride 72 ushorts (144B) kills conflicts
  __shared__ ushort_t sl[CT * 72];  // cols lo
  const int bi = blockIdx.x;
  const int rb = bi >> 1, half = bi & 1;
  const int tid = threadIdx.x;
  const int wave = tid >> 6, lane = tid & 63;
  const int n = lane & 15, quad = lane >> 4;
  const int row = rb * 64 + wave * 16 + n;
  const int b = row >= NPIX;
  const size_t cbase = (size_t)b * NPIX;

  // B-frags (this lane's row): B[k=quad*8+j][n=lane&15], kc1 at +32 elems (64B)
  const char* bp_h = (const char*)(nf_hi + (size_t)row * 64) + quad * 16;
  const char* bp_l = (const char*)(nf_lo + (size_t)row * 64) + quad * 16;
  const bf16x8 bh0 = *(const bf16x8*)(bp_h);
  const bf16x8 bh1 = *(const bf16x8*)(bp_h + 64);
  const bf16x8 bl0 = *(const bf16x8*)(bp_l);
  const bf16x8 bl1 = *(const bf16x8*)(bp_l + 64);

  float val[TK];
  int idx[TK];
#pragma unroll
  for (int i = 0; i < TK; ++i) { val[i] = -2.f; idx[i] = 0; }

  const int sc = tid >> 1;           // staging col 0..127
  const int sseg = (tid & 1) * 32;   // element offset (32 ushorts = 64B)

  for (int t = 0; t < NT; ++t) {
    const int cb = half * HALF_COLS + t * CT;
    __syncthreads();
    {
      const uint4* gh = (const uint4*)(nf_hi + (cbase + cb + sc) * 64 + sseg);
      const uint4* gl = (const uint4*)(nf_lo + (cbase + cb + sc) * 64 + sseg);
      uint4* dh = (uint4*)(sh + sc * 72 + sseg);
      uint4* dl = (uint4*)(sl + sc * 72 + sseg);
#pragma unroll
      for (int i = 0; i < 4; ++i) dh[i] = gh[i];
#pragma unroll
      for (int i = 0; i < 4; ++i) dl[i] = gl[i];
    }
    __syncthreads();

#pragma unroll 2
    for (int st = 0; st < 8; ++st) {
      // A-frags (cols): A[m=lane&15 within subtile][k=quad*8+j]
      const char* ap_h = (const char*)(sh + (st * 16 + n) * 72) + quad * 16;
      const char* ap_l = (const char*)(sl + (st * 16 + n) * 72) + quad * 16;
      bf16x8 ah0 = *(const bf16x8*)(ap_h);
      bf16x8 ah1 = *(const bf16x8*)(ap_h + 64);
      bf16x8 al0 = *(const bf16x8*)(ap_l);
      bf16x8 al1 = *(const bf16x8*)(ap_l + 64);
      f32x4 acc = {0.f, 0.f, 0.f, 0.f};
      acc = __builtin_amdgcn_mfma_f32_16x16x32_bf16(ah0, bh0, acc, 0, 0, 0);
      acc = __builtin_amdgcn_mfma_f32_16x16x32_bf16(ah1, bh1, acc, 0, 0, 0);
      acc = __builtin_amdgcn_mfma_f32_16x16x32_bf16(al0, bh0, acc, 0, 0, 0);
      acc = __builtin_amdgcn_mfma_f32_16x16x32_bf16(al1, bh1, acc, 0, 0, 0);
      acc = __builtin_amdgcn_mfma_f32_16x16x32_bf16(ah0, bl0, acc, 0, 0, 0);
      acc = __builtin_amdgcn_mfma_f32_16x16x32_bf16(ah1, bl1, acc, 0, 0, 0);
      acc = __builtin_amdgcn_mfma_f32_16x16x32_bf16(al0, bl0, acc, 0, 0, 0);
      acc = __builtin_amdgcn_mfma_f32_16x16x32_bf16(al1, bl1, acc, 0, 0, 0);

      const float mx4 = fmaxf(fmaxf(acc[0], acc[1]), fmaxf(acc[2], acc[3]));
      if (mx4 > val[0]) {
        const int c0 = cb + st * 16 + quad * 4;
#pragma unroll
        for (int r = 0; r < 4; ++r) {
          const float s = acc[r];
          if (s > val[0]) {
            const int m = c0 + r;
            float nv[TK];
            int ni[TK];
#pragma unroll
            for (int i = 0; i < TK - 1; ++i) {
              nv[i] = fminf(fmaxf(s, val[i]), val[i + 1]);
              ni[i] = (s > val[i]) ? ((s > val[i + 1]) ? idx[i + 1] : m) : idx[i];
            }
            nv[TK - 1] = fmaxf(s, val[TK - 1]);
            ni[TK - 1] = (s > val[TK - 1]) ? m : idx[TK - 1];
#pragma unroll
            for (int i = 0; i < TK; ++i) { val[i] = nv[i]; idx[i] = ni[i]; }
          }
        }
      }
    }
  }

  const size_t o = ((size_t)row * NS + half * 4 + quad) * TK;
#pragma unroll
  for (int i = 0; i < TK; ++i) {
    pval[o + i] = val[TK - 1 - i];
    pidx[o + i] = idx[TK - 1 - i];
  }
}

// ---------------- K3a: 8-way merge of partial top-16s + gather + mean ----------------
__global__ __launch_bounds__(256) void k_merge_gather(
    const float* __restrict__ nf, const float* __restrict__ pval,
    const int* __restrict__ pidx, float* __restrict__ corr) {
  const int row = blockIdx.x * 256 + threadIdx.x;
  const int b = row >= NPIX;
  const float* nfb = nf + (size_t)b * NPIX * RC;
  const size_t base = (size_t)row * NS * TK;

  int p[NS];
#pragma unroll
  for (int i = 0; i < NS; ++i) p[i] = 0;
  float4 acc[16];
#pragma unroll
  for (int i = 0; i < 16; ++i) acc[i] = make_float4(0.f, 0.f, 0.f, 0.f);

  for (int k = 0; k < TK; ++k) {
    float best = -1e30f;
    int bo = 0, bsel = 0;
#pragma unroll
    for (int si = 0; si < NS; ++si) {
      const int pp = p[si];
      const float h = (pp < TK) ? pval[base + si * TK + pp] : -1e30f;
      if (h > best) { best = h; bo = si * TK + pp; bsel = si; }  // strict >: lower slice wins ties
    }
    const int m = pidx[base + bo];
#pragma unroll
    for (int si = 0; si < NS; ++si) p[si] += (bsel == si);

    const float4* g = (const float4*)(nfb + (size_t)m * RC);
#pragma unroll
    for (int i = 0; i < 16; ++i) {
      float4 v = g[i];
      acc[i].x += v.x; acc[i].y += v.y; acc[i].z += v.z; acc[i].w += v.w;
    }
  }

  float4* o = (float4*)(corr + (size_t)row * RC);
#pragma unroll
  for (int i = 0; i < 16; ++i)
    o[i] = make_float4(acc[i].x * 0.0625f, acc[i].y * 0.0625f,
                       acc[i].z * 0.0625f, acc[i].w * 0.0625f);
}

// ---------------- K3b: proj back to C channels + residual add ----------------
__global__ __launch_bounds__(256) void k_proj_add(
    const float* __restrict__ x, const float* __restrict__ wp,
    const float* __restrict__ corr, float* __restrict__ out) {
  const int pg = blockIdx.x >> 2;
  const int cq = blockIdx.x & 3;
  const int tid = threadIdx.x;

  __shared__ float wl[64 * RC];
  {
    const float4* src = (const float4*)(wp + (size_t)cq * 64 * RC);
    float4* dst = (float4*)wl;
#pragma unroll
    for (int i = 0; i < 4; ++i) dst[i * 256 + tid] = src[i * 256 + tid];
  }

  const int p = pg * 256 + tid;
  const int b = p >= NPIX;
  const int n = p - b * NPIX;

  float4 cr[16];
  const float4* c4 = (const float4*)(corr + (size_t)p * RC);
#pragma unroll
  for (int i = 0; i < 16; ++i) cr[i] = c4[i];
  __syncthreads();

  const size_t xb = (size_t)b * NC * NPIX + n;
  for (int cl = 0; cl < 64; ++cl) {
    const float4* w4 = (const float4*)(wl + cl * RC);
    float s = 0.f;
#pragma unroll
    for (int i = 0; i < 16; ++i) {
      float4 w = w4[i];
      s += w.x * cr[i].x + w.y * cr[i].y + w.z * cr[i].z + w.w * cr[i].w;
    }
    const int c = cq * 64 + cl;
    const size_t oi = xb + (size_t)c * NPIX;
    out[oi] = x[oi] + s;
  }
}

extern "C" void kernel_launch(void* const* d_in, const int* in_sizes, int n_in,
                              void* d_out, int out_size, void* d_ws, size_t ws_size,
                              hipStream_t stream) {
  const float* x = (const float*)d_in[0];
  const float* wr = (const float*)d_in[1];
  const float* wp = (const float*)d_in[2];
  float* out = (float*)d_out;

  char* ws = (char*)d_ws;
  const size_t nf_bytes = (size_t)NROWS * RC * 4;               // 4,718,592
  const size_t hl_bytes = (size_t)NROWS * RC * 2;               // 2,359,296
  const size_t pv_bytes = (size_t)NROWS * NS * TK * 4;          // 9,437,184
  float* nf = (float*)ws;
  ushort_t* nf_hi = (ushort_t*)(ws + nf_bytes);
  ushort_t* nf_lo = (ushort_t*)(ws + nf_bytes + hl_bytes);
  float* pval = (float*)(ws + nf_bytes + 2 * hl_bytes);
  int* pidx = (int*)(ws + nf_bytes + 2 * hl_bytes + pv_bytes);
  float* corr = (float*)(ws + nf_bytes + 2 * hl_bytes + 2 * pv_bytes);
  // total ~33.0 MB

  hipLaunchKernelGGL(k_reduce_norm, dim3(NROWS / 256), dim3(256), 0, stream, x, wr, nf);
  hipLaunchKernelGGL(k_split, dim3((NROWS * RC / 8) / 256), dim3(256), 0, stream,
                     nf, nf_hi, nf_lo);
  hipLaunchKernelGGL(k_sim_topk, dim3((NROWS / 64) * 2), dim3(256), 0, stream,
                     nf_hi, nf_lo, pval, pidx);
  hipLaunchKernelGGL(k_merge_gather, dim3(NROWS / 256), dim3(256), 0, stream,
                     nf, pval, pidx, corr);
  hipLaunchKernelGGL(k_proj_add, dim3((NROWS / 256) * 4), dim3(256), 0, stream,
                     x, wp, corr, out);
}

// Round 3
// 390.914 us; speedup vs baseline: 6.2588x; 3.3591x over previous
//
#include <hip/hip_runtime.h>
#include <cstdint>
#include <cstddef>

#define NPIX 9216          // 96*96
#define NB 2
#define NC 256
#define RC 64
#define TK 16
#define NROWS (NB * NPIX)  // 18432
#define CT 128             // cols per LDS tile
#define QCOLS 2304         // cols per quarter
#define NT 18              // tiles per quarter
#define NSTR 16            // candidate streams per row (4 quarters x 4 quads)
#define CAP 10             // candidate slots per stream
#define MARGIN 0.004f      // covers |s_exact - s_hionly| <= 2*2^-9 + eps

typedef unsigned short ushort_t;
typedef unsigned int uint_t;
typedef __bf16 bf16x8 __attribute__((ext_vector_type(8)));
typedef float f32x4 __attribute__((ext_vector_type(4)));

__device__ __forceinline__ uint_t f2bf(float x) {
  uint_t u = __float_as_uint(x);
  return (u + 0x7FFFu + ((u >> 16) & 1u)) >> 16;
}

// ---------------- K1: 1x1 conv reduce -> feat[p][64] (r-quarter per block) ----------------
__global__ __launch_bounds__(256) void k_reduce(
    const float* __restrict__ x, const float* __restrict__ wr,
    float* __restrict__ feat) {
  __shared__ float wl[NC * 16];  // 16 KB: this block's 16 r-rows, transposed [c][16]
  const int pg = blockIdx.x >> 2, rq = blockIdx.x & 3;
  const int tid = threadIdx.x;  // tid == c for staging
#pragma unroll
  for (int i = 0; i < 16; ++i) wl[tid * 16 + i] = wr[(rq * 16 + i) * NC + tid];
  __syncthreads();

  const int p = pg * 256 + tid;
  const int b = p >= NPIX;
  const int n = p - b * NPIX;
  const float* xp = x + (size_t)b * NC * NPIX + n;

  float4 acc[4];
#pragma unroll
  for (int i = 0; i < 4; ++i) acc[i] = make_float4(0.f, 0.f, 0.f, 0.f);

  for (int c = 0; c < NC; ++c) {
    const float xv = xp[(size_t)c * NPIX];           // coalesced
    const float4* w4 = (const float4*)(wl + c * 16); // broadcast
#pragma unroll
    for (int i = 0; i < 4; ++i) {
      float4 w = w4[i];
      acc[i].x += w.x * xv; acc[i].y += w.y * xv;
      acc[i].z += w.z * xv; acc[i].w += w.w * xv;
    }
  }
  float4* o = (float4*)(feat + (size_t)p * RC + rq * 16);
#pragma unroll
  for (int i = 0; i < 4; ++i) o[i] = acc[i];
}

// ---------------- K1b: normalize + bf16 hi/lo split ----------------
__global__ __launch_bounds__(256) void k_normsplit(
    const float* __restrict__ feat, float* __restrict__ nf,
    ushort_t* __restrict__ hi, ushort_t* __restrict__ lo) {
  const int t = blockIdx.x * 256 + threadIdx.x;
  const int p = t >> 2, q = t & 3;  // 4 threads per pixel (lane-aligned quads)
  const float4* fp = (const float4*)(feat + (size_t)p * RC + q * 16);
  float4 v[4];
#pragma unroll
  for (int i = 0; i < 4; ++i) v[i] = fp[i];
  float ssq = 0.f;
#pragma unroll
  for (int i = 0; i < 4; ++i)
    ssq += v[i].x * v[i].x + v[i].y * v[i].y + v[i].z * v[i].z + v[i].w * v[i].w;
  ssq += __shfl_xor(ssq, 1);
  ssq += __shfl_xor(ssq, 2);
  const float inv = 1.f / fmaxf(sqrtf(ssq), 1e-12f);

  float s[16];
#pragma unroll
  for (int i = 0; i < 4; ++i) {
    s[i * 4 + 0] = v[i].x * inv; s[i * 4 + 1] = v[i].y * inv;
    s[i * 4 + 2] = v[i].z * inv; s[i * 4 + 3] = v[i].w * inv;
  }
  float4* no = (float4*)(nf + (size_t)p * RC + q * 16);
#pragma unroll
  for (int i = 0; i < 4; ++i)
    no[i] = make_float4(s[i * 4], s[i * 4 + 1], s[i * 4 + 2], s[i * 4 + 3]);

  uint_t hs[16], ls[16];
#pragma unroll
  for (int i = 0; i < 16; ++i) {
    hs[i] = f2bf(s[i]);
    ls[i] = f2bf(s[i] - __uint_as_float(hs[i] << 16));
  }
  uint4* ho = (uint4*)(hi + (size_t)p * RC + q * 16);
  uint4* lov = (uint4*)(lo + (size_t)p * RC + q * 16);
#pragma unroll
  for (int h = 0; h < 2; ++h) {
    ho[h] = make_uint4(hs[h*8+0] | (hs[h*8+1] << 16), hs[h*8+2] | (hs[h*8+3] << 16),
                       hs[h*8+4] | (hs[h*8+5] << 16), hs[h*8+6] | (hs[h*8+7] << 16));
    lov[h] = make_uint4(ls[h*8+0] | (ls[h*8+1] << 16), ls[h*8+2] | (ls[h*8+3] << 16),
                        ls[h*8+4] | (ls[h*8+5] << 16), ls[h*8+6] | (ls[h*8+7] << 16));
  }
}

// ---------------- K2a: pass A — hi-only sims, per-lane chunk maxima ----------------
// block = 128 rows x col-quarter; wave w: rows rb*128 + w*32 + {0..15, 16..31}
__global__ __launch_bounds__(256) void k_sim_max(
    const ushort_t* __restrict__ nf_hi, float* __restrict__ tmax) {
  __shared__ ushort_t sh[CT * 72];
  const int rb = blockIdx.x >> 2, q = blockIdx.x & 3;
  const int tid = threadIdx.x, wave = tid >> 6, lane = tid & 63;
  const int n = lane & 15, quad = lane >> 4;
  const int r0 = rb * 128 + wave * 32 + n, r1 = r0 + 16;
  const int b = rb >= 72;
  const size_t cbase = (size_t)b * NPIX;

  const bf16x8 bh00 = *(const bf16x8*)(nf_hi + (size_t)r0 * 64 + quad * 8);
  const bf16x8 bh01 = *(const bf16x8*)(nf_hi + (size_t)r0 * 64 + 32 + quad * 8);
  const bf16x8 bh10 = *(const bf16x8*)(nf_hi + (size_t)r1 * 64 + quad * 8);
  const bf16x8 bh11 = *(const bf16x8*)(nf_hi + (size_t)r1 * 64 + 32 + quad * 8);

  const int sc = tid >> 1, sseg = (tid & 1) * 32;
  float cm0 = -1e30f, cm1 = -1e30f;

  for (int t = 0; t < NT; ++t) {
    const int cb = q * QCOLS + t * CT;
    __syncthreads();
    {
      const uint4* g = (const uint4*)(nf_hi + (cbase + cb + sc) * 64 + sseg);
      uint4* d = (uint4*)(sh + sc * 72 + sseg);
#pragma unroll
      for (int i = 0; i < 4; ++i) d[i] = g[i];
    }
    __syncthreads();

#pragma unroll 2
    for (int st = 0; st < 8; ++st) {
      const ushort_t* ap = sh + (st * 16 + n) * 72 + quad * 8;
      bf16x8 ah0 = *(const bf16x8*)ap;
      bf16x8 ah1 = *(const bf16x8*)(ap + 32);
      f32x4 z = {0.f, 0.f, 0.f, 0.f};
      f32x4 a0 = __builtin_amdgcn_mfma_f32_16x16x32_bf16(ah0, bh00, z, 0, 0, 0);
      a0 = __builtin_amdgcn_mfma_f32_16x16x32_bf16(ah1, bh01, a0, 0, 0, 0);
      f32x4 a1 = __builtin_amdgcn_mfma_f32_16x16x32_bf16(ah0, bh10, z, 0, 0, 0);
      a1 = __builtin_amdgcn_mfma_f32_16x16x32_bf16(ah1, bh11, a1, 0, 0, 0);
      cm0 = fmaxf(cm0, fmaxf(fmaxf(a0[0], a0[1]), fmaxf(a0[2], a0[3])));
      cm1 = fmaxf(cm1, fmaxf(fmaxf(a1[0], a1[1]), fmaxf(a1[2], a1[3])));
    }
    if (t % 3 == 2) {  // chunk boundary (3 tiles = 96 cols per lane-stream)
      const int cn = t / 3;
      tmax[(size_t)r0 * 96 + (q * 4 + quad) * 6 + cn] = cm0;
      tmax[(size_t)r1 * 96 + (q * 4 + quad) * 6 + cn] = cm1;
      cm0 = -1e30f; cm1 = -1e30f;
    }
  }
}

// ---------------- K2b: threshold = 16th largest of 96 chunk maxima - margin ----------------
__global__ __launch_bounds__(256) void k_thresh(
    const float* __restrict__ tmax, float* __restrict__ Tb) {
  const int wave = threadIdx.x >> 6, lane = threadIdx.x & 63;
  const int row = blockIdx.x * 4 + wave;
  const float* tp = tmax + (size_t)row * 96;
  float v0 = tp[lane];
  float v1 = (lane < 32) ? tp[64 + lane] : -1e30f;
  float m = -1e30f;
#pragma unroll
  for (int k = 0; k < TK; ++k) {
    float c = fmaxf(v0, v1);
#pragma unroll
    for (int d = 1; d < 64; d <<= 1) c = fmaxf(c, __shfl_xor(c, d));
    m = c;
    if (v0 == m) v0 = -1e30f;  // killing duplicates only lowers T: safe
    if (v1 == m) v1 = -1e30f;
  }
  if (lane == 0) Tb[row] = m - MARGIN;
}

// ---------------- K2c: pass B — exact split sims, collect s >= T ----------------
__global__ __launch_bounds__(256) void k_collect(
    const ushort_t* __restrict__ nf_hi, const ushort_t* __restrict__ nf_lo,
    const float* __restrict__ Tb, float* __restrict__ cval,
    int* __restrict__ cidx, int* __restrict__ ccnt) {
  __shared__ ushort_t sh[CT * 72];
  __shared__ ushort_t sl[CT * 72];
  const int rb = blockIdx.x >> 2, q = blockIdx.x & 3;
  const int tid = threadIdx.x, wave = tid >> 6, lane = tid & 63;
  const int n = lane & 15, quad = lane >> 4;
  const int r0 = rb * 128 + wave * 32 + n, r1 = r0 + 16;
  const int b = rb >= 72;
  const size_t cbase = (size_t)b * NPIX;

  const bf16x8 bh00 = *(const bf16x8*)(nf_hi + (size_t)r0 * 64 + quad * 8);
  const bf16x8 bh01 = *(const bf16x8*)(nf_hi + (size_t)r0 * 64 + 32 + quad * 8);
  const bf16x8 bl00 = *(const bf16x8*)(nf_lo + (size_t)r0 * 64 + quad * 8);
  const bf16x8 bl01 = *(const bf16x8*)(nf_lo + (size_t)r0 * 64 + 32 + quad * 8);
  const bf16x8 bh10 = *(const bf16x8*)(nf_hi + (size_t)r1 * 64 + quad * 8);
  const bf16x8 bh11 = *(const bf16x8*)(nf_hi + (size_t)r1 * 64 + 32 + quad * 8);
  const bf16x8 bl10 = *(const bf16x8*)(nf_lo + (size_t)r1 * 64 + quad * 8);
  const bf16x8 bl11 = *(const bf16x8*)(nf_lo + (size_t)r1 * 64 + 32 + quad * 8);

  const float T0 = Tb[r0], T1 = Tb[r1];
  int cnt0 = 0, cnt1 = 0;
  const size_t base0 = ((size_t)r0 * 16 + q * 4 + quad) * CAP;
  const size_t base1 = ((size_t)r1 * 16 + q * 4 + quad) * CAP;

  const int sc = tid >> 1, sseg = (tid & 1) * 32;

  for (int t = 0; t < NT; ++t) {
    const int cb = q * QCOLS + t * CT;
    __syncthreads();
    {
      const uint4* gh = (const uint4*)(nf_hi + (cbase + cb + sc) * 64 + sseg);
      const uint4* gl = (const uint4*)(nf_lo + (cbase + cb + sc) * 64 + sseg);
      uint4* dh = (uint4*)(sh + sc * 72 + sseg);
      uint4* dl = (uint4*)(sl + sc * 72 + sseg);
#pragma unroll
      for (int i = 0; i < 4; ++i) dh[i] = gh[i];
#pragma unroll
      for (int i = 0; i < 4; ++i) dl[i] = gl[i];
    }
    __syncthreads();

    for (int st = 0; st < 8; ++st) {
      const ushort_t* aph = sh + (st * 16 + n) * 72 + quad * 8;
      const ushort_t* apl = sl + (st * 16 + n) * 72 + quad * 8;
      bf16x8 ah0 = *(const bf16x8*)aph;
      bf16x8 ah1 = *(const bf16x8*)(aph + 32);
      bf16x8 al0 = *(const bf16x8*)apl;
      bf16x8 al1 = *(const bf16x8*)(apl + 32);
      f32x4 z = {0.f, 0.f, 0.f, 0.f};
      f32x4 a0 = __builtin_amdgcn_mfma_f32_16x16x32_bf16(ah0, bh00, z, 0, 0, 0);
      a0 = __builtin_amdgcn_mfma_f32_16x16x32_bf16(ah1, bh01, a0, 0, 0, 0);
      a0 = __builtin_amdgcn_mfma_f32_16x16x32_bf16(al0, bh00, a0, 0, 0, 0);
      a0 = __builtin_amdgcn_mfma_f32_16x16x32_bf16(al1, bh01, a0, 0, 0, 0);
      a0 = __builtin_amdgcn_mfma_f32_16x16x32_bf16(ah0, bl00, a0, 0, 0, 0);
      a0 = __builtin_amdgcn_mfma_f32_16x16x32_bf16(ah1, bl01, a0, 0, 0, 0);
      a0 = __builtin_amdgcn_mfma_f32_16x16x32_bf16(al0, bl00, a0, 0, 0, 0);
      a0 = __builtin_amdgcn_mfma_f32_16x16x32_bf16(al1, bl01, a0, 0, 0, 0);
      f32x4 a1 = __builtin_amdgcn_mfma_f32_16x16x32_bf16(ah0, bh10, z, 0, 0, 0);
      a1 = __builtin_amdgcn_mfma_f32_16x16x32_bf16(ah1, bh11, a1, 0, 0, 0);
      a1 = __builtin_amdgcn_mfma_f32_16x16x32_bf16(al0, bh10, a1, 0, 0, 0);
      a1 = __builtin_amdgcn_mfma_f32_16x16x32_bf16(al1, bh11, a1, 0, 0, 0);
      a1 = __builtin_amdgcn_mfma_f32_16x16x32_bf16(ah0, bl10, a1, 0, 0, 0);
      a1 = __builtin_amdgcn_mfma_f32_16x16x32_bf16(ah1, bl11, a1, 0, 0, 0);
      a1 = __builtin_amdgcn_mfma_f32_16x16x32_bf16(al0, bl10, a1, 0, 0, 0);
      a1 = __builtin_amdgcn_mfma_f32_16x16x32_bf16(al1, bl11, a1, 0, 0, 0);

      const int c0 = cb + st * 16 + quad * 4;
      const float mx0 = fmaxf(fmaxf(a0[0], a0[1]), fmaxf(a0[2], a0[3]));
      if (mx0 >= T0) {
#pragma unroll
        for (int r = 0; r < 4; ++r)
          if (a0[r] >= T0 && cnt0 < CAP) {
            cval[base0 + cnt0] = a0[r]; cidx[base0 + cnt0] = c0 + r; cnt0++;
          }
      }
      const float mx1 = fmaxf(fmaxf(a1[0], a1[1]), fmaxf(a1[2], a1[3]));
      if (mx1 >= T1) {
#pragma unroll
        for (int r = 0; r < 4; ++r)
          if (a1[r] >= T1 && cnt1 < CAP) {
            cval[base1 + cnt1] = a1[r]; cidx[base1 + cnt1] = c0 + r; cnt1++;
          }
      }
    }
  }
  ccnt[r0 * 16 + q * 4 + quad] = cnt0;
  ccnt[r1 * 16 + q * 4 + quad] = cnt1;
}

// ---------------- K3a: exact top-16 over ~19 candidates + gather + mean ----------------
__global__ __launch_bounds__(256) void k_merge_gather(
    const float* __restrict__ nf, const float* __restrict__ cval,
    const int* __restrict__ cidx, const int* __restrict__ ccnt,
    float* __restrict__ corr) {
  __shared__ int lidx[256 * 17];
  const int rq = blockIdx.x & 3;
  const int row = (blockIdx.x >> 2) * 256 + threadIdx.x;
  const int b = row >= NPIX;
  const float* nfb = nf + (size_t)b * NPIX * RC;

  float val[TK];
  int idx[TK];
#pragma unroll
  for (int i = 0; i < TK; ++i) { val[i] = -1e30f; idx[i] = 0; }

  for (int s = 0; s < NSTR; ++s) {
    const int cn = ccnt[row * 16 + s];
    const size_t cb = ((size_t)row * 16 + s) * CAP;
    for (int j = 0; j < cn; ++j) {
      const float v = cval[cb + j];
      if (v > val[0]) {
        const int m = cidx[cb + j];
        float nv[TK];
        int ni[TK];
#pragma unroll
        for (int i = 0; i < TK - 1; ++i) {
          nv[i] = fminf(fmaxf(v, val[i]), val[i + 1]);
          ni[i] = (v > val[i]) ? ((v > val[i + 1]) ? idx[i + 1] : m) : idx[i];
        }
        nv[TK - 1] = fmaxf(v, val[TK - 1]);
        ni[TK - 1] = (v > val[TK - 1]) ? m : idx[TK - 1];
#pragma unroll
        for (int i = 0; i < TK; ++i) { val[i] = nv[i]; idx[i] = ni[i]; }
      }
    }
  }

#pragma unroll
  for (int i = 0; i < TK; ++i) lidx[threadIdx.x * 17 + i] = idx[i];

  float4 acc[4];
#pragma unroll
  for (int i = 0; i < 4; ++i) acc[i] = make_float4(0.f, 0.f, 0.f, 0.f);
  for (int k = 0; k < TK; ++k) {
    const int m = lidx[threadIdx.x * 17 + k];
    const float4* g = (const float4*)(nfb + (size_t)m * RC + rq * 16);
#pragma unroll
    for (int i = 0; i < 4; ++i) {
      float4 v = g[i];
      acc[i].x += v.x; acc[i].y += v.y; acc[i].z += v.z; acc[i].w += v.w;
    }
  }
  float4* o = (float4*)(corr + (size_t)row * RC + rq * 16);
#pragma unroll
  for (int i = 0; i < 4; ++i)
    o[i] = make_float4(acc[i].x * 0.0625f, acc[i].y * 0.0625f,
                       acc[i].z * 0.0625f, acc[i].w * 0.0625f);
}

// ---------------- K3b: proj back to C channels + residual add ----------------
__global__ __launch_bounds__(256) void k_proj_add(
    const float* __restrict__ x, const float* __restrict__ wp,
    const float* __restrict__ corr, float* __restrict__ out) {
  const int pg = blockIdx.x >> 2;
  const int cq = blockIdx.x & 3;
  const int tid = threadIdx.x;

  __shared__ float wl[64 * RC];
  {
    const float4* src = (const float4*)(wp + (size_t)cq * 64 * RC);
    float4* dst = (float4*)wl;
#pragma unroll
    for (int i = 0; i < 4; ++i) dst[i * 256 + tid] = src[i * 256 + tid];
  }

  const int p = pg * 256 + tid;
  const int b = p >= NPIX;
  const int n = p - b * NPIX;

  float4 cr[16];
  const float4* c4 = (const float4*)(corr + (size_t)p * RC);
#pragma unroll
  for (int i = 0; i < 16; ++i) cr[i] = c4[i];
  __syncthreads();

  const size_t xb = (size_t)b * NC * NPIX + n;
  for (int cl = 0; cl < 64; ++cl) {
    const float4* w4 = (const float4*)(wl + cl * RC);
    float s = 0.f;
#pragma unroll
    for (int i = 0; i < 16; ++i) {
      float4 w = w4[i];
      s += w.x * cr[i].x + w.y * cr[i].y + w.z * cr[i].z + w.w * cr[i].w;
    }
    const int c = cq * 64 + cl;
    const size_t oi = xb + (size_t)c * NPIX;
    out[oi] = x[oi] + s;
  }
}

extern "C" void kernel_launch(void* const* d_in, const int* in_sizes, int n_in,
                              void* d_out, int out_size, void* d_ws, size_t ws_size,
                              hipStream_t stream) {
  const float* x = (const float*)d_in[0];
  const float* wr = (const float*)d_in[1];
  const float* wp = (const float*)d_in[2];
  float* out = (float*)d_out;

  char* ws = (char*)d_ws;
  // region1 (7,077,888 B) time-shares: feat (k_reduce->k_normsplit),
  // tmax (k_sim_max->k_thresh), corr (k_merge->k_proj) — lifetimes disjoint.
  float* feat = (float*)ws;
  float* tmax = (float*)ws;
  float* corr = (float*)ws;
  float* nf = (float*)(ws + 7077888);
  ushort_t* nf_hi = (ushort_t*)(ws + 11796480);
  ushort_t* nf_lo = (ushort_t*)(ws + 14155776);
  float* Tb = (float*)(ws + 16515072);
  int* ccnt = (int*)(ws + 16588800);
  float* cval = (float*)(ws + 17768448);
  int* cidx = (int*)(ws + 29564928);
  // total 41,361,408 B

  hipLaunchKernelGGL(k_reduce, dim3(288), dim3(256), 0, stream, x, wr, feat);
  hipLaunchKernelGGL(k_normsplit, dim3(288), dim3(256), 0, stream, feat, nf, nf_hi, nf_lo);
  hipLaunchKernelGGL(k_sim_max, dim3(576), dim3(256), 0, stream, nf_hi, tmax);
  hipLaunchKernelGGL(k_thresh, dim3(NROWS / 4), dim3(256), 0, stream, tmax, Tb);
  hipLaunchKernelGGL(k_collect, dim3(576), dim3(256), 0, stream,
                     nf_hi, nf_lo, Tb, cval, cidx, ccnt);
  hipLaunchKernelGGL(k_merge_gather, dim3(288), dim3(256), 0, stream,
                     nf, cval, cidx, ccnt, corr);
  hipLaunchKernelGGL(k_proj_add, dim3(288), dim3(256), 0, stream, x, wp, corr, out);
}

// Round 4
// 311.642 us; speedup vs baseline: 7.8508x; 1.2544x over previous
//
#include <hip/hip_runtime.h>
#include <cstdint>
#include <cstddef>

#define NPIX 9216          // 96*96
#define NB 2
#define NC 256
#define RC 64
#define TK 16
#define NROWS (NB * NPIX)  // 18432
#define CT 128             // cols per LDS tile
#define ECOLS 1152         // cols per eighth
#define NTE 9              // tiles per eighth
#define MAXC 128           // compact candidate slots per row
#define MARGIN 0.008f      // 2*e, e <= 2.01*2^-9 * ||a||*||b|| = 3.93e-3

typedef unsigned short ushort_t;
typedef unsigned int uint_t;
typedef __bf16 bf16x8 __attribute__((ext_vector_type(8)));
typedef float f32x4 __attribute__((ext_vector_type(4)));

__device__ __forceinline__ uint_t f2bf(float x) {
  uint_t u = __float_as_uint(x);
  return (u + 0x7FFFu + ((u >> 16) & 1u)) >> 16;
}

// monotone float->uint map (bigger float => bigger uint)
__device__ __forceinline__ uint_t ordu(float v) {
  uint_t u = __float_as_uint(v);
  return (u & 0x80000000u) ? ~u : (u | 0x80000000u);
}

// ---------------- K1: 1x1 conv reduce, c-split partials ----------------
// grid: 72 pixgroups x 4 rq x 4 cq = 1152. feat4 layout [rq*4+cq][NROWS][16]
__global__ __launch_bounds__(256) void k_reduce(
    const float* __restrict__ x, const float* __restrict__ wr,
    float* __restrict__ feat4) {
  __shared__ float wl[64 * 16];  // 4 KB: [c_local][r_local]
  const int bi = blockIdx.x;
  const int pg = bi >> 4, rq = (bi >> 2) & 3, cq = bi & 3;
  const int tid = threadIdx.x;
  {
    const int cl = tid >> 2, rg = (tid & 3) * 4;
#pragma unroll
    for (int i = 0; i < 4; ++i)
      wl[cl * 16 + rg + i] = wr[(size_t)(rq * 16 + rg + i) * NC + cq * 64 + cl];
  }
  __syncthreads();

  const int p = pg * 256 + tid;
  const int b = p >= NPIX;
  const int n = p - b * NPIX;
  const float* xp = x + (size_t)b * NC * NPIX + (size_t)cq * 64 * NPIX + n;

  float4 acc[4];
#pragma unroll
  for (int i = 0; i < 4; ++i) acc[i] = make_float4(0.f, 0.f, 0.f, 0.f);

  for (int c = 0; c < 64; ++c) {
    const float xv = xp[(size_t)c * NPIX];           // coalesced
    const float4* w4 = (const float4*)(wl + c * 16); // broadcast
#pragma unroll
    for (int i = 0; i < 4; ++i) {
      float4 w = w4[i];
      acc[i].x += w.x * xv; acc[i].y += w.y * xv;
      acc[i].z += w.z * xv; acc[i].w += w.w * xv;
    }
  }
  float4* o = (float4*)(feat4 + (((size_t)(rq * 4 + cq)) * NROWS + p) * 16);
#pragma unroll
  for (int i = 0; i < 4; ++i) o[i] = acc[i];  // 64B/lane contiguous
}

// ---------------- K1b: sum partials + normalize + bf16 hi ----------------
__global__ __launch_bounds__(256) void k_normsplit(
    const float* __restrict__ feat4, float* __restrict__ nf,
    ushort_t* __restrict__ hi) {
  const int t = blockIdx.x * 256 + threadIdx.x;
  const int p = t >> 2, q = t & 3;  // 4 lanes per pixel
  float4 v[4];
#pragma unroll
  for (int i = 0; i < 4; ++i) v[i] = make_float4(0.f, 0.f, 0.f, 0.f);
#pragma unroll
  for (int pt = 0; pt < 4; ++pt) {
    const float4* fp = (const float4*)(feat4 + (((size_t)(q * 4 + pt)) * NROWS + p) * 16);
#pragma unroll
    for (int i = 0; i < 4; ++i) {
      float4 a = fp[i];
      v[i].x += a.x; v[i].y += a.y; v[i].z += a.z; v[i].w += a.w;
    }
  }
  float ssq = 0.f;
#pragma unroll
  for (int i = 0; i < 4; ++i)
    ssq += v[i].x * v[i].x + v[i].y * v[i].y + v[i].z * v[i].z + v[i].w * v[i].w;
  ssq += __shfl_xor(ssq, 1);
  ssq += __shfl_xor(ssq, 2);
  const float inv = 1.f / fmaxf(sqrtf(ssq), 1e-12f);

  float s[16];
#pragma unroll
  for (int i = 0; i < 4; ++i) {
    s[i * 4 + 0] = v[i].x * inv; s[i * 4 + 1] = v[i].y * inv;
    s[i * 4 + 2] = v[i].z * inv; s[i * 4 + 3] = v[i].w * inv;
  }
  float4* no = (float4*)(nf + (size_t)p * RC + q * 16);
#pragma unroll
  for (int i = 0; i < 4; ++i)
    no[i] = make_float4(s[i * 4], s[i * 4 + 1], s[i * 4 + 2], s[i * 4 + 3]);

  uint_t hs[16];
#pragma unroll
  for (int i = 0; i < 16; ++i) hs[i] = f2bf(s[i]);
  uint4* ho = (uint4*)(hi + (size_t)p * RC + q * 16);
#pragma unroll
  for (int h = 0; h < 2; ++h)
    ho[h] = make_uint4(hs[h*8+0] | (hs[h*8+1] << 16), hs[h*8+2] | (hs[h*8+3] << 16),
                       hs[h*8+4] | (hs[h*8+5] << 16), hs[h*8+6] | (hs[h*8+7] << 16));
}

// ---------------- K2a: pass A — hi sims, per-lane chunk maxima ----------------
// grid: 144 rowblocks(128 rows) x 8 col-eighths = 1152
__global__ __launch_bounds__(256) void k_sim_max(
    const ushort_t* __restrict__ nf_hi, float* __restrict__ tmax) {
  __shared__ ushort_t sh[CT * 72];
  const int rb = blockIdx.x >> 3, q = blockIdx.x & 7;
  const int tid = threadIdx.x, wave = tid >> 6, lane = tid & 63;
  const int n = lane & 15, quad = lane >> 4;
  const int r0 = rb * 128 + wave * 32 + n, r1 = r0 + 16;
  const int b = rb >= 72;
  const size_t cbase = (size_t)b * NPIX;

  const bf16x8 bh00 = *(const bf16x8*)(nf_hi + (size_t)r0 * 64 + quad * 8);
  const bf16x8 bh01 = *(const bf16x8*)(nf_hi + (size_t)r0 * 64 + 32 + quad * 8);
  const bf16x8 bh10 = *(const bf16x8*)(nf_hi + (size_t)r1 * 64 + quad * 8);
  const bf16x8 bh11 = *(const bf16x8*)(nf_hi + (size_t)r1 * 64 + 32 + quad * 8);

  const int sc = tid >> 1, sseg = (tid & 1) * 32;
  float cm0 = -1e30f, cm1 = -1e30f;

  for (int t = 0; t < NTE; ++t) {
    const int cb = q * ECOLS + t * CT;
    __syncthreads();
    {
      const uint4* g = (const uint4*)(nf_hi + (cbase + cb + sc) * 64 + sseg);
      uint4* d = (uint4*)(sh + sc * 72 + sseg);
#pragma unroll
      for (int i = 0; i < 4; ++i) d[i] = g[i];
    }
    __syncthreads();

#pragma unroll 2
    for (int st = 0; st < 8; ++st) {
      const ushort_t* ap = sh + (st * 16 + n) * 72 + quad * 8;
      bf16x8 ah0 = *(const bf16x8*)ap;
      bf16x8 ah1 = *(const bf16x8*)(ap + 32);
      f32x4 z = {0.f, 0.f, 0.f, 0.f};
      f32x4 a0 = __builtin_amdgcn_mfma_f32_16x16x32_bf16(ah0, bh00, z, 0, 0, 0);
      a0 = __builtin_amdgcn_mfma_f32_16x16x32_bf16(ah1, bh01, a0, 0, 0, 0);
      f32x4 a1 = __builtin_amdgcn_mfma_f32_16x16x32_bf16(ah0, bh10, z, 0, 0, 0);
      a1 = __builtin_amdgcn_mfma_f32_16x16x32_bf16(ah1, bh11, a1, 0, 0, 0);
      cm0 = fmaxf(cm0, fmaxf(fmaxf(a0[0], a0[1]), fmaxf(a0[2], a0[3])));
      cm1 = fmaxf(cm1, fmaxf(fmaxf(a1[0], a1[1]), fmaxf(a1[2], a1[3])));
    }
    if (t % 3 == 2) {  // 3 tiles = 96 cols per lane-stream chunk
      const int cn = t / 3;
      tmax[(size_t)r0 * 96 + (q * 4 + quad) * 3 + cn] = cm0;
      tmax[(size_t)r1 * 96 + (q * 4 + quad) * 3 + cn] = cm1;
      cm0 = -1e30f; cm1 = -1e30f;
    }
  }
}

// ---------------- K2b: threshold = 16th largest of 96 chunk maxima - margin ----------------
__global__ __launch_bounds__(256) void k_thresh(
    const float* __restrict__ tmax, float* __restrict__ Tb) {
  const int wave = threadIdx.x >> 6, lane = threadIdx.x & 63;
  const int row = blockIdx.x * 4 + wave;
  const float* tp = tmax + (size_t)row * 96;
  float v0 = tp[lane];
  float v1 = (lane < 32) ? tp[64 + lane] : -1e30f;
  float m = -1e30f;
#pragma unroll
  for (int k = 0; k < TK; ++k) {
    float c = fmaxf(v0, v1);
#pragma unroll
    for (int d = 1; d < 64; d <<= 1) c = fmaxf(c, __shfl_xor(c, d));
    m = c;
    if (v0 == m) v0 = -1e30f;  // killing duplicates only lowers T: safe
    if (v1 == m) v1 = -1e30f;
  }
  if (lane == 0) Tb[row] = m - MARGIN;
}

// ---------------- K2c: pass B — hi sims again, append cols with s_hi >= T ----------------
__global__ __launch_bounds__(256) void k_collect(
    const ushort_t* __restrict__ nf_hi, const float* __restrict__ Tb,
    int* __restrict__ cidx, int* __restrict__ rowcnt) {
  __shared__ ushort_t sh[CT * 72];
  const int rb = blockIdx.x >> 3, q = blockIdx.x & 7;
  const int tid = threadIdx.x, wave = tid >> 6, lane = tid & 63;
  const int n = lane & 15, quad = lane >> 4;
  const int r0 = rb * 128 + wave * 32 + n, r1 = r0 + 16;
  const int b = rb >= 72;
  const size_t cbase = (size_t)b * NPIX;

  const bf16x8 bh00 = *(const bf16x8*)(nf_hi + (size_t)r0 * 64 + quad * 8);
  const bf16x8 bh01 = *(const bf16x8*)(nf_hi + (size_t)r0 * 64 + 32 + quad * 8);
  const bf16x8 bh10 = *(const bf16x8*)(nf_hi + (size_t)r1 * 64 + quad * 8);
  const bf16x8 bh11 = *(const bf16x8*)(nf_hi + (size_t)r1 * 64 + 32 + quad * 8);

  const float T0 = Tb[r0], T1 = Tb[r1];
  const int sc = tid >> 1, sseg = (tid & 1) * 32;

  for (int t = 0; t < NTE; ++t) {
    const int cb = q * ECOLS + t * CT;
    __syncthreads();
    {
      const uint4* g = (const uint4*)(nf_hi + (cbase + cb + sc) * 64 + sseg);
      uint4* d = (uint4*)(sh + sc * 72 + sseg);
#pragma unroll
      for (int i = 0; i < 4; ++i) d[i] = g[i];
    }
    __syncthreads();

#pragma unroll 2
    for (int st = 0; st < 8; ++st) {
      const ushort_t* ap = sh + (st * 16 + n) * 72 + quad * 8;
      bf16x8 ah0 = *(const bf16x8*)ap;
      bf16x8 ah1 = *(const bf16x8*)(ap + 32);
      f32x4 z = {0.f, 0.f, 0.f, 0.f};
      f32x4 a0 = __builtin_amdgcn_mfma_f32_16x16x32_bf16(ah0, bh00, z, 0, 0, 0);
      a0 = __builtin_amdgcn_mfma_f32_16x16x32_bf16(ah1, bh01, a0, 0, 0, 0);
      f32x4 a1 = __builtin_amdgcn_mfma_f32_16x16x32_bf16(ah0, bh10, z, 0, 0, 0);
      a1 = __builtin_amdgcn_mfma_f32_16x16x32_bf16(ah1, bh11, a1, 0, 0, 0);

      const int c0 = cb + st * 16 + quad * 4;
      const float mx0 = fmaxf(fmaxf(a0[0], a0[1]), fmaxf(a0[2], a0[3]));
      if (mx0 >= T0) {
#pragma unroll
        for (int r = 0; r < 4; ++r)
          if (a0[r] >= T0) {
            const int slot = atomicAdd(rowcnt + r0, 1);
            if (slot < MAXC) cidx[(size_t)r0 * MAXC + slot] = c0 + r;
          }
      }
      const float mx1 = fmaxf(fmaxf(a1[0], a1[1]), fmaxf(a1[2], a1[3]));
      if (mx1 >= T1) {
#pragma unroll
        for (int r = 0; r < 4; ++r)
          if (a1[r] >= T1) {
            const int slot = atomicAdd(rowcnt + r1, 1);
            if (slot < MAXC) cidx[(size_t)r1 * MAXC + slot] = c0 + r;
          }
      }
    }
  }
}

// ---------------- K3: exact fp32 dots on candidates + top-16 + gather + mean ----------------
// wave per 4 rows; grid NROWS/16 = 1152
__global__ __launch_bounds__(256) void k_merge_gather(
    const float* __restrict__ nf, const int* __restrict__ cidx,
    const int* __restrict__ rowcnt, float* __restrict__ corr) {
  const int wave = threadIdx.x >> 6, lane = threadIdx.x & 63;
  const int row0 = blockIdx.x * 16 + wave * 4;
#pragma unroll 1
  for (int rr = 0; rr < 4; ++rr) {
    const int row = row0 + rr;
    const int b = row >= NPIX;
    const int rl = row - b * NPIX;
    const float* nfb = nf + (size_t)b * NPIX * RC;
    const int C = min(rowcnt[row], MAXC);

    float4 rv[16];
    const float4* r4 = (const float4*)(nf + (size_t)row * RC);
#pragma unroll
    for (int i = 0; i < 16; ++i) rv[i] = r4[i];  // broadcast loads

    const int* cp = cidx + (size_t)row * MAXC;
    unsigned long long k0 = 0, k1 = 0;
    {
      const int c0 = (lane < C) ? cp[lane] : rl;
      const float4* g = (const float4*)(nfb + (size_t)c0 * RC);
      float s = 0.f;
#pragma unroll
      for (int i = 0; i < 16; ++i) {
        float4 a = g[i];
        s += a.x * rv[i].x + a.y * rv[i].y + a.z * rv[i].z + a.w * rv[i].w;
      }
      if (lane < C)
        k0 = ((unsigned long long)ordu(s) << 32) | (uint_t)(~(uint_t)c0);
    }
    if (C > 64) {  // wave-uniform branch, rare
      const int c1 = (64 + lane < C) ? cp[64 + lane] : rl;
      const float4* g = (const float4*)(nfb + (size_t)c1 * RC);
      float s = 0.f;
#pragma unroll
      for (int i = 0; i < 16; ++i) {
        float4 a = g[i];
        s += a.x * rv[i].x + a.y * rv[i].y + a.z * rv[i].z + a.w * rv[i].w;
      }
      if (64 + lane < C)
        k1 = ((unsigned long long)ordu(s) << 32) | (uint_t)(~(uint_t)c1);
    }

    int sel[TK];
#pragma unroll
    for (int t = 0; t < TK; ++t) {
      unsigned long long m = k0 > k1 ? k0 : k1;
#pragma unroll
      for (int d = 1; d < 64; d <<= 1) {
        unsigned long long o = __shfl_xor(m, d);
        m = (o > m) ? o : m;
      }
      sel[t] = (m == 0) ? rl : (int)(~(uint_t)(m & 0xFFFFFFFFull));
      if (k0 == m) k0 = 0;
      else if (k1 == m) k1 = 0;
    }

    float acc = 0.f;
#pragma unroll
    for (int t = 0; t < TK; ++t)
      acc += nfb[(size_t)sel[t] * RC + lane];  // coalesced 256B per t
    corr[(size_t)row * RC + lane] = acc * 0.0625f;
  }
}

// ---------------- K4: proj back to C channels + residual add ----------------
// grid: 72 pixgroups x 8 channel-eighths = 576
__global__ __launch_bounds__(256) void k_proj_add(
    const float* __restrict__ x, const float* __restrict__ wp,
    const float* __restrict__ corr, float* __restrict__ out) {
  const int pg = blockIdx.x >> 3, cq = blockIdx.x & 7;
  const int tid = threadIdx.x;

  __shared__ float wl[32 * RC];  // 8 KB
  {
    const float4* src = (const float4*)(wp + (size_t)cq * 32 * RC);
    float4* dst = (float4*)wl;
#pragma unroll
    for (int i = 0; i < 2; ++i) dst[i * 256 + tid] = src[i * 256 + tid];
  }

  const int p = pg * 256 + tid;
  const int b = p >= NPIX;
  const int n = p - b * NPIX;

  float4 cr[16];
  const float4* c4 = (const float4*)(corr + (size_t)p * RC);
#pragma unroll
  for (int i = 0; i < 16; ++i) cr[i] = c4[i];
  __syncthreads();

  const size_t xb = (size_t)b * NC * NPIX + n;
  for (int cl = 0; cl < 32; ++cl) {
    const float4* w4 = (const float4*)(wl + cl * RC);  // broadcast
    float s = 0.f;
#pragma unroll
    for (int i = 0; i < 16; ++i) {
      float4 w = w4[i];
      s += w.x * cr[i].x + w.y * cr[i].y + w.z * cr[i].z + w.w * cr[i].w;
    }
    const int c = cq * 32 + cl;
    const size_t oi = xb + (size_t)c * NPIX;
    out[oi] = x[oi] + s;  // coalesced
  }
}

extern "C" void kernel_launch(void* const* d_in, const int* in_sizes, int n_in,
                              void* d_out, int out_size, void* d_ws, size_t ws_size,
                              hipStream_t stream) {
  const float* x = (const float*)d_in[0];
  const float* wr = (const float*)d_in[1];
  const float* wp = (const float*)d_in[2];
  float* out = (float*)d_out;

  char* ws = (char*)d_ws;
  // region1 (18,874,368 B) time-shares: feat4 (reduce->normsplit),
  // tmax (sim_max->thresh), corr (merge->proj) — lifetimes disjoint.
  float* feat4 = (float*)ws;
  float* tmax = (float*)ws;
  float* corr = (float*)ws;
  float* nf = (float*)(ws + 18874368);
  ushort_t* nf_hi = (ushort_t*)(ws + 23592960);
  float* Tb = (float*)(ws + 25952256);
  int* rowcnt = (int*)(ws + 26025984);
  int* cidx = (int*)(ws + 26099712);
  // total 35,536,896 B

  hipLaunchKernelGGL(k_reduce, dim3(1152), dim3(256), 0, stream, x, wr, feat4);
  hipLaunchKernelGGL(k_normsplit, dim3(288), dim3(256), 0, stream, feat4, nf, nf_hi);
  hipLaunchKernelGGL(k_sim_max, dim3(1152), dim3(256), 0, stream, nf_hi, tmax);
  hipLaunchKernelGGL(k_thresh, dim3(NROWS / 4), dim3(256), 0, stream, tmax, Tb);
  hipMemsetAsync(rowcnt, 0, NROWS * sizeof(int), stream);
  hipLaunchKernelGGL(k_collect, dim3(1152), dim3(256), 0, stream,
                     nf_hi, Tb, cidx, rowcnt);
  hipLaunchKernelGGL(k_merge_gather, dim3(1152), dim3(256), 0, stream,
                     nf, cidx, rowcnt, corr);
  hipLaunchKernelGGL(k_proj_add, dim3(576), dim3(256), 0, stream, x, wp, corr, out);
}